// Round 8
// baseline (106.279 us; speedup 1.0000x reference)
//
#include <hip/hip_runtime.h>
#include <hip/hip_bf16.h>

// Fused 3-layer GCN + mean-pool + mask, FP8(e4m3), BARRIER-FREE design:
// one 64-lane wave per graph does everything (A-build + 4 GEMMs + BN + pool).
// Single-wave LDS ops are processed in program order -> zero __syncthreads().
// In-place LDS activation buffer; each GEMM preloads its A-operand fragments
// to 64 VGPRs before overwriting. Layer 3 eliminated:
//   pooled*128 = (csum^T H2) W3,  csum = A^T 1.
// Grid 512 x 64 thr; LDS 36.9KB/WG -> 2 WGs/CU resident (grid-capped; waves
// are the latency-hiding unit, phase barriers were the old bottleneck).
//
// LDS: An[0,16K) fp8 A_norm swizzled (u4 cnt overlay [0,8K)),
//      Ab[16K,32K) fp8 activation (X -> XW1^T -> H1 -> Ht2), misc @32K.

#define NGRAPH 512
#define EPG 1024
#define NEDGE (NGRAPH * EPG)
#define NEGV -10000000000.0f
#define LDS_SOLO 36864

typedef float f32x16 __attribute__((ext_vector_type(16)));
typedef float f32x4  __attribute__((ext_vector_type(4)));

#define MFMA8(a, b, c) __builtin_amdgcn_mfma_f32_32x32x16_fp8_fp8(a, b, c, 0, 0, 0)

__device__ unsigned char g_wf[32768];   // fp8 W1/W2 fragment buffer

// 128B rows; XOR row into the 8B-slot bits -> 2-way max on b64 reads
__device__ __forceinline__ unsigned swz8(unsigned row, unsigned byte_in_row) {
  return ((row << 7) + byte_in_row) ^ ((row & 15u) << 3);
}

__device__ __forceinline__ unsigned pk4(float a, float b, float c, float d) {
  int r = __builtin_amdgcn_cvt_pk_fp8_f32(a, b, 0, false);
  r = __builtin_amdgcn_cvt_pk_fp8_f32(c, d, r, true);
  return (unsigned)r;
}

// W [fi][fo] f32 -> fragment-ordered fp8 W^T, 8B per (layer,nt,ks,lane)
__global__ void prep_w(const float* __restrict__ W1, const float* __restrict__ W2) {
  int gid = blockIdx.x * 256 + threadIdx.x;     // 0..4095, 8 fp8 each
  int lyr = gid >> 11, r = gid & 2047;
  int lane = r & 63, ks = (r >> 6) & 7, nt = r >> 9;
  const float* W = lyr ? W2 : W1;
  int fo = nt * 32 + (lane & 31);
  int k0 = ks * 16 + (lane >> 5) * 8;
  uint2 o;
  o.x = pk4(W[(k0 + 0) * 128 + fo], W[(k0 + 1) * 128 + fo],
            W[(k0 + 2) * 128 + fo], W[(k0 + 3) * 128 + fo]);
  o.y = pk4(W[(k0 + 4) * 128 + fo], W[(k0 + 5) * 128 + fo],
            W[(k0 + 6) * 128 + fo], W[(k0 + 7) * 128 + fo]);
  ((uint2*)g_wf)[gid] = o;
}

__global__ __launch_bounds__(64, 2) void gcn_solo(
    const float* __restrict__ x, const int* __restrict__ ei,
    const float* __restrict__ b1v, const float* __restrict__ g1v,
    const float* __restrict__ be1v, const float* __restrict__ rm1v,
    const float* __restrict__ rv1v,
    const float* __restrict__ b2v, const float* __restrict__ g2v,
    const float* __restrict__ be2v, const float* __restrict__ rm2v,
    const float* __restrict__ rv2v,
    const float* __restrict__ W3g, const float* __restrict__ b3v,
    float* __restrict__ out) {
  extern __shared__ char sm[];
  char* AnB = sm;                          // fp8[128][128] swizzled
  char* AbB = sm + 16384;                  // fp8[128][128] swizzled
  unsigned* cntW = (unsigned*)sm;          // u4 counts overlay [0,8K)
  float*    dis  = (float*)(sm + 32768);
  unsigned* deg  = (unsigned*)(sm + 33280);
  float*    csum = (float*)(sm + 33792);
  float*    scl1 = (float*)(sm + 34304);
  float*    shf1 = (float*)(sm + 34816);
  float*    scl2 = (float*)(sm + 35328);
  float*    shf2 = (float*)(sm + 35840);
  float*    vred = (float*)(sm + 36352);

  const int l = threadIdx.x;               // 0..63 (one wave)
  const int g = blockIdx.x;
  const int l31 = l & 31, hi = l >> 5;
  const int n0 = 2 * l, n1 = 2 * l + 1;    // this lane's two nodes/features

  // ---- issue small global loads first ----
  int es[16], ed[16];
#pragma unroll
  for (int j = 0; j < 16; ++j) {
    int e = g * EPG + l + 64 * j;
    es[j] = ei[e] & 127;
    ed[j] = ei[NEDGE + e] & 127;
  }
  float2 rv1p = *(const float2*)(rv1v + n0);
  float2 g1p  = *(const float2*)(g1v + n0);
  float2 be1p = *(const float2*)(be1v + n0);
  float2 b1p  = *(const float2*)(b1v + n0);
  float2 rm1p = *(const float2*)(rm1v + n0);
  float2 rv2p = *(const float2*)(rv2v + n0);
  float2 g2p  = *(const float2*)(g2v + n0);
  float2 be2p = *(const float2*)(be2v + n0);
  float2 b2p  = *(const float2*)(b2v + n0);
  float2 rm2p = *(const float2*)(rm2v + n0);
  long w1f[4][8];
#pragma unroll
  for (int nt = 0; nt < 4; ++nt)
#pragma unroll
    for (int ks = 0; ks < 8; ++ks)
      w1f[nt][ks] = *(const long*)(g_wf + nt * 4096 + ks * 512 + l * 8);

  const f32x4* xgf = (const f32x4*)(x + (size_t)g * 128 * 128);
  // x-stream chunk: 8 f32x4 per lane -> fp8 into Ab (interleaved with A-build)
#define XCHUNK(c)                                                           \
  {                                                                         \
    _Pragma("unroll") for (int i = 0; i < 8; ++i) {                         \
      int k = l + 64 * ((c) * 8 + i);                                       \
      f32x4 v = xgf[k];                                                     \
      *(unsigned*)(AbB + swz8(k >> 5, (k & 31) * 4)) =                      \
          pk4(v[0], v[1], v[2], v[3]);                                      \
    }                                                                       \
  }

  XCHUNK(0); XCHUNK(1);

  // zero cnt (8KB), deg init
  uint4 z; z.x = 0; z.y = 0; z.z = 0; z.w = 0;
#pragma unroll
  for (int i = 0; i < 8; ++i) ((uint4*)cntW)[l + 64 * i] = z;
  *(uint2*)(deg + n0) = make_uint2(1u, 1u);
  // BN params (bias folded into shift)
  {
    float s1a = rsqrtf(rv1p.x + 1e-5f) * g1p.x;
    float s1b = rsqrtf(rv1p.y + 1e-5f) * g1p.y;
    *(float2*)(scl1 + n0) = make_float2(s1a, s1b);
    *(float2*)(shf1 + n0) = make_float2(be1p.x + (b1p.x - rm1p.x) * s1a,
                                        be1p.y + (b1p.y - rm1p.y) * s1b);
    float s2a = rsqrtf(rv2p.x + 1e-5f) * g2p.x;
    float s2b = rsqrtf(rv2p.y + 1e-5f) * g2p.y;
    *(float2*)(scl2 + n0) = make_float2(s2a, s2b);
    *(float2*)(shf2 + n0) = make_float2(be2p.x + (b2p.x - rm2p.x) * s2a,
                                        be2p.y + (b2p.y - rm2p.y) * s2b);
  }

  XCHUNK(2); XCHUNK(3);

  // edge count + degree atomics (wave-private LDS, in-order)
#pragma unroll
  for (int j = 0; j < 16; ++j) {
    atomicAdd(&cntW[ed[j] * 16 + (es[j] >> 3)], 1u << (4 * (es[j] & 7)));
    atomicAdd(&deg[ed[j]], 1u);
  }

  XCHUNK(4); XCHUNK(5);

  unsigned d0 = deg[n0], d1 = deg[n1];
  float dv0 = rsqrtf((float)d0), dv1 = rsqrtf((float)d1);
  *(float2*)(dis + n0) = make_float2(dv0, dv1);
  *(float2*)(csum + n0) = make_float2(dv0 * dv0, dv1 * dv1);
#pragma unroll
  for (int j = 0; j < 16; ++j)
    atomicAdd(&csum[es[j]], dis[es[j]] * dis[ed[j]]);

  XCHUNK(6); XCHUNK(7);
#undef XCHUNK

  // ---- cnt -> An fp8 (rows n0, n1); all reads precede all writes ----
  uint4 cw[8];
#pragma unroll
  for (int i = 0; i < 8; ++i) cw[i] = ((const uint4*)cntW)[8 * l + i];
#pragma unroll
  for (int rr = 0; rr < 2; ++rr) {
    int row = n0 + rr;
    float dd = rr ? dv1 : dv0;
#pragma unroll
    for (int q = 0; q < 4; ++q) {
      uint4 cq = cw[rr * 4 + q];
      unsigned w4[4] = {cq.x, cq.y, cq.z, cq.w};
#pragma unroll
      for (int jj = 0; jj < 4; ++jj) {
        unsigned w = w4[jj];
        int s0 = q * 32 + jj * 8;
        f32x4 da = *(const f32x4*)(dis + s0);
        f32x4 db = *(const f32x4*)(dis + s0 + 4);
        float v[8];
#pragma unroll
        for (int i = 0; i < 8; ++i) {
          float cf = (float)((w >> (4 * i)) & 15u);
          float val = cf * dd * (i < 4 ? da[i] : db[i - 4]);
          if (s0 + i == row) val += dd * dd;    // self loop
          v[i] = val;
        }
        uint2 o;
        o.x = pk4(v[0], v[1], v[2], v[3]);
        o.y = pk4(v[4], v[5], v[6], v[7]);
        *(uint2*)(AnB + swz8(row, s0)) = o;
      }
    }
  }

  // ---- S0: XW1^T = (X @ W1)^T : A=X frags (preload), B=W1 regs ----
  long fr[4][8];
#pragma unroll
  for (int mt = 0; mt < 4; ++mt)
#pragma unroll
    for (int ks = 0; ks < 8; ++ks)
      fr[mt][ks] = *(const long*)(AbB + swz8(mt * 32 + l31, ks * 16 + hi * 8));
#pragma unroll
  for (int ns = 0; ns < 4; ++ns) {
    f32x16 a0 = {}, a1 = {}, a2 = {}, a3 = {};
#pragma unroll
    for (int ks = 0; ks < 8; ++ks) {
      a0 = MFMA8(fr[0][ks], w1f[ns][ks], a0);
      a1 = MFMA8(fr[1][ks], w1f[ns][ks], a1);
      a2 = MFMA8(fr[2][ks], w1f[ns][ks], a2);
      a3 = MFMA8(fr[3][ks], w1f[ns][ks], a3);
    }
    int col = ns * 32 + l31;                    // fo
#pragma unroll
    for (int mt = 0; mt < 4; ++mt) {
      const f32x16& a = mt == 0 ? a0 : mt == 1 ? a1 : mt == 2 ? a2 : a3;
#pragma unroll
      for (int q = 0; q < 4; ++q)
        *(unsigned*)(AbB + swz8(col, mt * 32 + q * 8 + hi * 4)) =
            pk4(a[q * 4 + 0], a[q * 4 + 1], a[q * 4 + 2], a[q * 4 + 3]);
    }
  }

  // ---- S1: (A @ XW1)^T -> BN1+ReLU -> H1[d][f] ; B=An from LDS ----
#pragma unroll
  for (int mt = 0; mt < 4; ++mt)
#pragma unroll
    for (int ks = 0; ks < 8; ++ks)
      fr[mt][ks] = *(const long*)(AbB + swz8(mt * 32 + l31, ks * 16 + hi * 8));
  long w2f[4][8];
#pragma unroll
  for (int nt = 0; nt < 4; ++nt)                // issue early; used in S2
#pragma unroll
    for (int ks = 0; ks < 8; ++ks)
      w2f[nt][ks] = *(const long*)(g_wf + 16384 + nt * 4096 + ks * 512 + l * 8);
#pragma unroll
  for (int ns = 0; ns < 4; ++ns) {
    f32x16 a0 = {}, a1 = {}, a2 = {}, a3 = {};
#pragma unroll
    for (int ks = 0; ks < 8; ++ks) {
      long b = *(const long*)(AnB + swz8(ns * 32 + l31, ks * 16 + hi * 8));
      a0 = MFMA8(fr[0][ks], b, a0);
      a1 = MFMA8(fr[1][ks], b, a1);
      a2 = MFMA8(fr[2][ks], b, a2);
      a3 = MFMA8(fr[3][ks], b, a3);
    }
    int col = ns * 32 + l31;                    // d (node)
#pragma unroll
    for (int mt = 0; mt < 4; ++mt) {
      const f32x16& a = mt == 0 ? a0 : mt == 1 ? a1 : mt == 2 ? a2 : a3;
#pragma unroll
      for (int q = 0; q < 4; ++q) {
        int f0 = mt * 32 + q * 8 + hi * 4;
        f32x4 s4 = *(const f32x4*)(scl1 + f0);
        f32x4 h4 = *(const f32x4*)(shf1 + f0);
        *(unsigned*)(AbB + swz8(col, f0)) =
            pk4(fmaxf(a[q * 4 + 0] * s4[0] + h4[0], 0.f),
                fmaxf(a[q * 4 + 1] * s4[1] + h4[1], 0.f),
                fmaxf(a[q * 4 + 2] * s4[2] + h4[2], 0.f),
                fmaxf(a[q * 4 + 3] * s4[3] + h4[3], 0.f));
      }
    }
  }

  // ---- S2: Ht2 = (H1 @ W2)^T ; A=H1 frags, B=W2 regs ----
#pragma unroll
  for (int mt = 0; mt < 4; ++mt)
#pragma unroll
    for (int ks = 0; ks < 8; ++ks)
      fr[mt][ks] = *(const long*)(AbB + swz8(mt * 32 + l31, ks * 16 + hi * 8));
#pragma unroll
  for (int ns = 0; ns < 4; ++ns) {
    f32x16 a0 = {}, a1 = {}, a2 = {}, a3 = {};
#pragma unroll
    for (int ks = 0; ks < 8; ++ks) {
      a0 = MFMA8(fr[0][ks], w2f[ns][ks], a0);
      a1 = MFMA8(fr[1][ks], w2f[ns][ks], a1);
      a2 = MFMA8(fr[2][ks], w2f[ns][ks], a2);
      a3 = MFMA8(fr[3][ks], w2f[ns][ks], a3);
    }
    int col = ns * 32 + l31;                    // fo
#pragma unroll
    for (int mt = 0; mt < 4; ++mt) {
      const f32x16& a = mt == 0 ? a0 : mt == 1 ? a1 : mt == 2 ? a2 : a3;
#pragma unroll
      for (int q = 0; q < 4; ++q)
        *(unsigned*)(AbB + swz8(col, mt * 32 + q * 8 + hi * 4)) =
            pk4(a[q * 4 + 0], a[q * 4 + 1], a[q * 4 + 2], a[q * 4 + 3]);
    }
  }

  // ---- S3: (A @ H1W2)^T -> BN2+ReLU -> weighted colsum (vred) ----
#pragma unroll
  for (int mt = 0; mt < 4; ++mt)
#pragma unroll
    for (int ks = 0; ks < 8; ++ks)
      fr[mt][ks] = *(const long*)(AbB + swz8(mt * 32 + l31, ks * 16 + hi * 8));
  f32x16 vf0 = {}, vf1 = {}, vf2 = {}, vf3 = {};
#pragma unroll
  for (int ns = 0; ns < 4; ++ns) {
    f32x16 a0 = {}, a1 = {}, a2 = {}, a3 = {};
#pragma unroll
    for (int ks = 0; ks < 8; ++ks) {
      long b = *(const long*)(AnB + swz8(ns * 32 + l31, ks * 16 + hi * 8));
      a0 = MFMA8(fr[0][ks], b, a0);
      a1 = MFMA8(fr[1][ks], b, a1);
      a2 = MFMA8(fr[2][ks], b, a2);
      a3 = MFMA8(fr[3][ks], b, a3);
    }
    float cs = csum[ns * 32 + l31];             // weight of this node-column
#pragma unroll
    for (int mt = 0; mt < 4; ++mt) {
      const f32x16& a = mt == 0 ? a0 : mt == 1 ? a1 : mt == 2 ? a2 : a3;
      f32x16& vf = mt == 0 ? vf0 : mt == 1 ? vf1 : mt == 2 ? vf2 : vf3;
#pragma unroll
      for (int q = 0; q < 4; ++q) {
        int f0 = mt * 32 + q * 8 + hi * 4;
        f32x4 s4 = *(const f32x4*)(scl2 + f0);
        f32x4 h4 = *(const f32x4*)(shf2 + f0);
#pragma unroll
        for (int j = 0; j < 4; ++j)
          vf[q * 4 + j] += cs * fmaxf(a[q * 4 + j] * s4[j] + h4[j], 0.f);
      }
    }
  }
  // reduce over the 32 node-columns (l31 groups)
#pragma unroll
  for (int mt = 0; mt < 4; ++mt) {
    f32x16& vf = mt == 0 ? vf0 : mt == 1 ? vf1 : mt == 2 ? vf2 : vf3;
#pragma unroll
    for (int e = 0; e < 16; ++e) {
      float s = vf[e];
      s += __shfl_xor(s, 1, 32);
      s += __shfl_xor(s, 2, 32);
      s += __shfl_xor(s, 4, 32);
      s += __shfl_xor(s, 8, 32);
      s += __shfl_xor(s, 16, 32);
      vf[e] = s;
    }
  }
  if (l31 == 0) {                               // lanes 0 and 32 write vred
#pragma unroll
    for (int mt = 0; mt < 4; ++mt) {
      const f32x16& vf = mt == 0 ? vf0 : mt == 1 ? vf1 : mt == 2 ? vf2 : vf3;
#pragma unroll
      for (int q = 0; q < 4; ++q) {
        f32x4 t;
        t[0] = vf[q * 4 + 0]; t[1] = vf[q * 4 + 1];
        t[2] = vf[q * 4 + 2]; t[3] = vf[q * 4 + 3];
        *(f32x4*)(vred + mt * 32 + q * 8 + hi * 4) = t;
      }
    }
  }

  // ---- matvec: vout[fo] = sum_fi vred[fi] * W3[fi][fo] ----
  float acc0 = 0.f, acc1 = 0.f;
#pragma unroll 8
  for (int f4 = 0; f4 < 32; ++f4) {
    f32x4 vr = *(const f32x4*)(vred + f4 * 4);  // broadcast read
#pragma unroll
    for (int t = 0; t < 4; ++t) {
      float2 w = *(const float2*)(W3g + (f4 * 4 + t) * 128 + n0);
      acc0 += vr[t] * w.x;
      acc1 += vr[t] * w.y;
    }
  }

  // ---- mask + output ----
  float2 b3p = *(const float2*)(b3v + n0);
  float cs0 = csum[n0], cs1 = csum[n1];
  bool c0 = (d0 != 1u) || (cs0 != dv0 * dv0);   // node used as dst or src
  bool c1 = (d1 != 1u) || (cs1 != dv1 * dv1);
  unsigned long long bl0 = __ballot(c0 ? 1 : 0);
  unsigned long long bl1 = __ballot(c1 ? 1 : 0);
  int m0 = bl0 ? 2 * __builtin_ctzll(bl0) : (1 << 30);
  int m1 = bl1 ? 2 * __builtin_ctzll(bl1) + 1 : (1 << 30);
  int minid = m0 < m1 ? m0 : m1;
  float v0 = acc0 * (1.0f / 128.0f) + b3p.x;
  float v1 = acc1 * (1.0f / 128.0f) + b3p.y;
  float2 o;
  o.x = (c0 && n0 != minid) ? NEGV : v0;
  o.y = (c1 && n1 != minid) ? NEGV : v1;
  *(float2*)(out + (size_t)g * 128 + n0) = o;
}

extern "C" void kernel_launch(void* const* d_in, const int* in_sizes, int n_in,
                              void* d_out, int out_size, void* d_ws, size_t ws_size,
                              hipStream_t stream) {
  (void)in_sizes; (void)n_in; (void)out_size; (void)d_ws; (void)ws_size;
  const float* x   = (const float*)d_in[0];
  const int*   ei  = (const int*)d_in[1];
  // d_in[2] = batch (unused; graphs are contiguous 128-node blocks)
  const float* W1  = (const float*)d_in[3];
  const float* b1  = (const float*)d_in[4];
  const float* g1  = (const float*)d_in[5];
  const float* be1 = (const float*)d_in[6];
  const float* rm1 = (const float*)d_in[7];
  const float* rv1 = (const float*)d_in[8];
  const float* W2  = (const float*)d_in[9];
  const float* b2  = (const float*)d_in[10];
  const float* g2  = (const float*)d_in[11];
  const float* be2 = (const float*)d_in[12];
  const float* rm2 = (const float*)d_in[13];
  const float* rv2 = (const float*)d_in[14];
  const float* W3  = (const float*)d_in[15];
  const float* b3  = (const float*)d_in[16];

  prep_w<<<dim3(16), dim3(256), 0, stream>>>(W1, W2);
  gcn_solo<<<dim3(NGRAPH), dim3(64), LDS_SOLO, stream>>>(
      x, ei, b1, g1, be1, rm1, rv1, b2, g2, be2, rm2, rv2, W3, b3,
      (float*)d_out);
}

// Round 9
// 79.405 us; speedup vs baseline: 1.3384x; 1.3384x over previous
//
#include <hip/hip_runtime.h>
#include <hip/hip_bf16.h>

// Fused 3-layer GCN + mean-pool + mask, FP8(e4m3), BARRIER-FREE:
// one 64-lane wave per graph (A-build + 4 GEMMs + BN + pool), zero barriers
// (single-wave LDS ops are in program order). In-place LDS activation buffer;
// GEMMs that overwrite their own input preload A-fragments to 64 VGPRs.
// Layer 3 eliminated: pooled*128 = (csum^T H2) W3, csum = A^T 1.
// Round-9 fix vs round 8: __launch_bounds__(64,1) (512-reg budget; grid-capped
// at 2 waves/CU anyway) and W2 fragments read from L2 in-loop (-64 VGPR) ->
// no scratch spills (round 8: 63MB scratch writes, 157us).
//
// LDS: An[0,16K) fp8 A_norm swizzled (u4 cnt overlay [0,8K)),
//      Ab[16K,32K) fp8 activation (X -> XW1^T -> H1 -> Ht2), misc @32K.

#define NGRAPH 512
#define EPG 1024
#define NEDGE (NGRAPH * EPG)
#define NEGV -10000000000.0f
#define LDS_SOLO 36864

typedef float f32x16 __attribute__((ext_vector_type(16)));
typedef float f32x4  __attribute__((ext_vector_type(4)));

#define MFMA8(a, b, c) __builtin_amdgcn_mfma_f32_32x32x16_fp8_fp8(a, b, c, 0, 0, 0)

__device__ unsigned char g_wf[32768];   // fp8 W1/W2 fragment buffer

// 128B rows; XOR row into the 8B-slot bits -> 2-way max on b64 reads
__device__ __forceinline__ unsigned swz8(unsigned row, unsigned byte_in_row) {
  return ((row << 7) + byte_in_row) ^ ((row & 15u) << 3);
}

__device__ __forceinline__ unsigned pk4(float a, float b, float c, float d) {
  int r = __builtin_amdgcn_cvt_pk_fp8_f32(a, b, 0, false);
  r = __builtin_amdgcn_cvt_pk_fp8_f32(c, d, r, true);
  return (unsigned)r;
}

// W [fi][fo] f32 -> fragment-ordered fp8 W^T, 8B per (layer,nt,ks,lane)
__global__ void prep_w(const float* __restrict__ W1, const float* __restrict__ W2) {
  int gid = blockIdx.x * 256 + threadIdx.x;     // 0..4095, 8 fp8 each
  int lyr = gid >> 11, r = gid & 2047;
  int lane = r & 63, ks = (r >> 6) & 7, nt = r >> 9;
  const float* W = lyr ? W2 : W1;
  int fo = nt * 32 + (lane & 31);
  int k0 = ks * 16 + (lane >> 5) * 8;
  uint2 o;
  o.x = pk4(W[(k0 + 0) * 128 + fo], W[(k0 + 1) * 128 + fo],
            W[(k0 + 2) * 128 + fo], W[(k0 + 3) * 128 + fo]);
  o.y = pk4(W[(k0 + 4) * 128 + fo], W[(k0 + 5) * 128 + fo],
            W[(k0 + 6) * 128 + fo], W[(k0 + 7) * 128 + fo]);
  ((uint2*)g_wf)[gid] = o;
}

__global__ __launch_bounds__(64, 1) void gcn_solo(
    const float* __restrict__ x, const int* __restrict__ ei,
    const float* __restrict__ b1v, const float* __restrict__ g1v,
    const float* __restrict__ be1v, const float* __restrict__ rm1v,
    const float* __restrict__ rv1v,
    const float* __restrict__ b2v, const float* __restrict__ g2v,
    const float* __restrict__ be2v, const float* __restrict__ rm2v,
    const float* __restrict__ rv2v,
    const float* __restrict__ W3g, const float* __restrict__ b3v,
    float* __restrict__ out) {
  extern __shared__ char sm[];
  char* AnB = sm;                          // fp8[128][128] swizzled
  char* AbB = sm + 16384;                  // fp8[128][128] swizzled
  unsigned* cntW = (unsigned*)sm;          // u4 counts overlay [0,8K)
  float*    dis  = (float*)(sm + 32768);
  unsigned* deg  = (unsigned*)(sm + 33280);
  float*    csum = (float*)(sm + 33792);
  float*    scl1 = (float*)(sm + 34304);
  float*    shf1 = (float*)(sm + 34816);
  float*    scl2 = (float*)(sm + 35328);
  float*    shf2 = (float*)(sm + 35840);
  float*    vred = (float*)(sm + 36352);

  const int l = threadIdx.x;               // 0..63 (one wave)
  const int g = blockIdx.x;
  const int l31 = l & 31, hi = l >> 5;
  const int n0 = 2 * l, n1 = 2 * l + 1;    // this lane's two nodes/features

  // ---- issue small global loads first ----
  int es[16], ed[16];
#pragma unroll
  for (int j = 0; j < 16; ++j) {
    int e = g * EPG + l + 64 * j;
    es[j] = ei[e] & 127;
    ed[j] = ei[NEDGE + e] & 127;
  }
  float2 rv1p = *(const float2*)(rv1v + n0);
  float2 g1p  = *(const float2*)(g1v + n0);
  float2 be1p = *(const float2*)(be1v + n0);
  float2 b1p  = *(const float2*)(b1v + n0);
  float2 rm1p = *(const float2*)(rm1v + n0);
  float2 rv2p = *(const float2*)(rv2v + n0);
  float2 g2p  = *(const float2*)(g2v + n0);
  float2 be2p = *(const float2*)(be2v + n0);
  float2 b2p  = *(const float2*)(b2v + n0);
  float2 rm2p = *(const float2*)(rm2v + n0);
  long w1f[4][8];
#pragma unroll
  for (int nt = 0; nt < 4; ++nt)
#pragma unroll
    for (int ks = 0; ks < 8; ++ks)
      w1f[nt][ks] = *(const long*)(g_wf + nt * 4096 + ks * 512 + l * 8);

  const f32x4* xgf = (const f32x4*)(x + (size_t)g * 128 * 128);
  // x-stream chunk: 8 f32x4 per lane -> fp8 into Ab (interleaved with A-build)
#define XCHUNK(c)                                                           \
  {                                                                         \
    _Pragma("unroll") for (int i = 0; i < 8; ++i) {                         \
      int k = l + 64 * ((c) * 8 + i);                                       \
      f32x4 v = xgf[k];                                                     \
      *(unsigned*)(AbB + swz8(k >> 5, (k & 31) * 4)) =                      \
          pk4(v[0], v[1], v[2], v[3]);                                      \
    }                                                                       \
  }

  XCHUNK(0); XCHUNK(1);

  // zero cnt (8KB), deg init
  uint4 z; z.x = 0; z.y = 0; z.z = 0; z.w = 0;
#pragma unroll
  for (int i = 0; i < 8; ++i) ((uint4*)cntW)[l + 64 * i] = z;
  *(uint2*)(deg + n0) = make_uint2(1u, 1u);
  // BN params (bias folded into shift)
  {
    float s1a = rsqrtf(rv1p.x + 1e-5f) * g1p.x;
    float s1b = rsqrtf(rv1p.y + 1e-5f) * g1p.y;
    *(float2*)(scl1 + n0) = make_float2(s1a, s1b);
    *(float2*)(shf1 + n0) = make_float2(be1p.x + (b1p.x - rm1p.x) * s1a,
                                        be1p.y + (b1p.y - rm1p.y) * s1b);
    float s2a = rsqrtf(rv2p.x + 1e-5f) * g2p.x;
    float s2b = rsqrtf(rv2p.y + 1e-5f) * g2p.y;
    *(float2*)(scl2 + n0) = make_float2(s2a, s2b);
    *(float2*)(shf2 + n0) = make_float2(be2p.x + (b2p.x - rm2p.x) * s2a,
                                        be2p.y + (b2p.y - rm2p.y) * s2b);
  }

  XCHUNK(2); XCHUNK(3);

  // edge count + degree atomics (wave-private LDS, in-order)
#pragma unroll
  for (int j = 0; j < 16; ++j) {
    atomicAdd(&cntW[ed[j] * 16 + (es[j] >> 3)], 1u << (4 * (es[j] & 7)));
    atomicAdd(&deg[ed[j]], 1u);
  }

  XCHUNK(4); XCHUNK(5);

  unsigned d0 = deg[n0], d1 = deg[n1];
  float dv0 = rsqrtf((float)d0), dv1 = rsqrtf((float)d1);
  *(float2*)(dis + n0) = make_float2(dv0, dv1);
  *(float2*)(csum + n0) = make_float2(dv0 * dv0, dv1 * dv1);
#pragma unroll
  for (int j = 0; j < 16; ++j)
    atomicAdd(&csum[es[j]], dis[es[j]] * dis[ed[j]]);

  XCHUNK(6); XCHUNK(7);
#undef XCHUNK

  // ---- cnt -> An fp8 (rows n0, n1); all reads precede all writes ----
  uint4 cw[8];
#pragma unroll
  for (int i = 0; i < 8; ++i) cw[i] = ((const uint4*)cntW)[8 * l + i];
#pragma unroll
  for (int rr = 0; rr < 2; ++rr) {
    int row = n0 + rr;
    float dd = rr ? dv1 : dv0;
#pragma unroll
    for (int q = 0; q < 4; ++q) {
      uint4 cq = cw[rr * 4 + q];
      unsigned w4[4] = {cq.x, cq.y, cq.z, cq.w};
#pragma unroll
      for (int jj = 0; jj < 4; ++jj) {
        unsigned w = w4[jj];
        int s0 = q * 32 + jj * 8;
        f32x4 da = *(const f32x4*)(dis + s0);
        f32x4 db = *(const f32x4*)(dis + s0 + 4);
        float v[8];
#pragma unroll
        for (int i = 0; i < 8; ++i) {
          float cf = (float)((w >> (4 * i)) & 15u);
          float val = cf * dd * (i < 4 ? da[i] : db[i - 4]);
          if (s0 + i == row) val += dd * dd;    // self loop
          v[i] = val;
        }
        uint2 o;
        o.x = pk4(v[0], v[1], v[2], v[3]);
        o.y = pk4(v[4], v[5], v[6], v[7]);
        *(uint2*)(AnB + swz8(row, s0)) = o;
      }
    }
  }

  // ---- S0: XW1^T = (X @ W1)^T : A=X frags (preload), B=W1 regs ----
  long fr[4][8];
#pragma unroll
  for (int mt = 0; mt < 4; ++mt)
#pragma unroll
    for (int ks = 0; ks < 8; ++ks)
      fr[mt][ks] = *(const long*)(AbB + swz8(mt * 32 + l31, ks * 16 + hi * 8));
#pragma unroll
  for (int ns = 0; ns < 4; ++ns) {
    f32x16 a0 = {}, a1 = {}, a2 = {}, a3 = {};
#pragma unroll
    for (int ks = 0; ks < 8; ++ks) {
      a0 = MFMA8(fr[0][ks], w1f[ns][ks], a0);
      a1 = MFMA8(fr[1][ks], w1f[ns][ks], a1);
      a2 = MFMA8(fr[2][ks], w1f[ns][ks], a2);
      a3 = MFMA8(fr[3][ks], w1f[ns][ks], a3);
    }
    int col = ns * 32 + l31;                    // fo
#pragma unroll
    for (int mt = 0; mt < 4; ++mt) {
      const f32x16& a = mt == 0 ? a0 : mt == 1 ? a1 : mt == 2 ? a2 : a3;
#pragma unroll
      for (int q = 0; q < 4; ++q)
        *(unsigned*)(AbB + swz8(col, mt * 32 + q * 8 + hi * 4)) =
            pk4(a[q * 4 + 0], a[q * 4 + 1], a[q * 4 + 2], a[q * 4 + 3]);
    }
  }

  // ---- S1: (A @ XW1)^T -> BN1+ReLU -> H1[d][f] ; B=An from LDS ----
#pragma unroll
  for (int mt = 0; mt < 4; ++mt)
#pragma unroll
    for (int ks = 0; ks < 8; ++ks)
      fr[mt][ks] = *(const long*)(AbB + swz8(mt * 32 + l31, ks * 16 + hi * 8));
#pragma unroll
  for (int ns = 0; ns < 4; ++ns) {
    f32x16 a0 = {}, a1 = {}, a2 = {}, a3 = {};
#pragma unroll
    for (int ks = 0; ks < 8; ++ks) {
      long b = *(const long*)(AnB + swz8(ns * 32 + l31, ks * 16 + hi * 8));
      a0 = MFMA8(fr[0][ks], b, a0);
      a1 = MFMA8(fr[1][ks], b, a1);
      a2 = MFMA8(fr[2][ks], b, a2);
      a3 = MFMA8(fr[3][ks], b, a3);
    }
    int col = ns * 32 + l31;                    // d (node)
#pragma unroll
    for (int mt = 0; mt < 4; ++mt) {
      const f32x16& a = mt == 0 ? a0 : mt == 1 ? a1 : mt == 2 ? a2 : a3;
#pragma unroll
      for (int q = 0; q < 4; ++q) {
        int f0 = mt * 32 + q * 8 + hi * 4;
        f32x4 s4 = *(const f32x4*)(scl1 + f0);
        f32x4 h4 = *(const f32x4*)(shf1 + f0);
        *(unsigned*)(AbB + swz8(col, f0)) =
            pk4(fmaxf(a[q * 4 + 0] * s4[0] + h4[0], 0.f),
                fmaxf(a[q * 4 + 1] * s4[1] + h4[1], 0.f),
                fmaxf(a[q * 4 + 2] * s4[2] + h4[2], 0.f),
                fmaxf(a[q * 4 + 3] * s4[3] + h4[3], 0.f));
      }
    }
  }

  // ---- S2: Ht2 = (H1 @ W2)^T ; A=H1 frags, B=W2 from L2 in-loop ----
#pragma unroll
  for (int mt = 0; mt < 4; ++mt)
#pragma unroll
    for (int ks = 0; ks < 8; ++ks)
      fr[mt][ks] = *(const long*)(AbB + swz8(mt * 32 + l31, ks * 16 + hi * 8));
#pragma unroll
  for (int ns = 0; ns < 4; ++ns) {
    f32x16 a0 = {}, a1 = {}, a2 = {}, a3 = {};
#pragma unroll
    for (int ks = 0; ks < 8; ++ks) {
      long b = *(const long*)(g_wf + 16384 + ns * 4096 + ks * 512 + l * 8);
      a0 = MFMA8(fr[0][ks], b, a0);
      a1 = MFMA8(fr[1][ks], b, a1);
      a2 = MFMA8(fr[2][ks], b, a2);
      a3 = MFMA8(fr[3][ks], b, a3);
    }
    int col = ns * 32 + l31;                    // fo
#pragma unroll
    for (int mt = 0; mt < 4; ++mt) {
      const f32x16& a = mt == 0 ? a0 : mt == 1 ? a1 : mt == 2 ? a2 : a3;
#pragma unroll
      for (int q = 0; q < 4; ++q)
        *(unsigned*)(AbB + swz8(col, mt * 32 + q * 8 + hi * 4)) =
            pk4(a[q * 4 + 0], a[q * 4 + 1], a[q * 4 + 2], a[q * 4 + 3]);
    }
  }

  // ---- S3: (A @ H1W2)^T -> BN2+ReLU -> weighted colsum (vred) ----
#pragma unroll
  for (int mt = 0; mt < 4; ++mt)
#pragma unroll
    for (int ks = 0; ks < 8; ++ks)
      fr[mt][ks] = *(const long*)(AbB + swz8(mt * 32 + l31, ks * 16 + hi * 8));
  f32x16 vf0 = {}, vf1 = {}, vf2 = {}, vf3 = {};
#pragma unroll
  for (int ns = 0; ns < 4; ++ns) {
    f32x16 a0 = {}, a1 = {}, a2 = {}, a3 = {};
#pragma unroll
    for (int ks = 0; ks < 8; ++ks) {
      long b = *(const long*)(AnB + swz8(ns * 32 + l31, ks * 16 + hi * 8));
      a0 = MFMA8(fr[0][ks], b, a0);
      a1 = MFMA8(fr[1][ks], b, a1);
      a2 = MFMA8(fr[2][ks], b, a2);
      a3 = MFMA8(fr[3][ks], b, a3);
    }
    float cs = csum[ns * 32 + l31];             // weight of this node-column
#pragma unroll
    for (int mt = 0; mt < 4; ++mt) {
      const f32x16& a = mt == 0 ? a0 : mt == 1 ? a1 : mt == 2 ? a2 : a3;
      f32x16& vf = mt == 0 ? vf0 : mt == 1 ? vf1 : mt == 2 ? vf2 : vf3;
#pragma unroll
      for (int q = 0; q < 4; ++q) {
        int f0 = mt * 32 + q * 8 + hi * 4;
        f32x4 s4 = *(const f32x4*)(scl2 + f0);
        f32x4 h4 = *(const f32x4*)(shf2 + f0);
#pragma unroll
        for (int j = 0; j < 4; ++j)
          vf[q * 4 + j] += cs * fmaxf(a[q * 4 + j] * s4[j] + h4[j], 0.f);
      }
    }
  }
  // reduce over the 32 node-columns (l31 groups)
#pragma unroll
  for (int mt = 0; mt < 4; ++mt) {
    f32x16& vf = mt == 0 ? vf0 : mt == 1 ? vf1 : mt == 2 ? vf2 : vf3;
#pragma unroll
    for (int e = 0; e < 16; ++e) {
      float s = vf[e];
      s += __shfl_xor(s, 1, 32);
      s += __shfl_xor(s, 2, 32);
      s += __shfl_xor(s, 4, 32);
      s += __shfl_xor(s, 8, 32);
      s += __shfl_xor(s, 16, 32);
      vf[e] = s;
    }
  }
  if (l31 == 0) {                               // lanes 0 and 32 write vred
#pragma unroll
    for (int mt = 0; mt < 4; ++mt) {
      const f32x16& vf = mt == 0 ? vf0 : mt == 1 ? vf1 : mt == 2 ? vf2 : vf3;
#pragma unroll
      for (int q = 0; q < 4; ++q) {
        f32x4 t;
        t[0] = vf[q * 4 + 0]; t[1] = vf[q * 4 + 1];
        t[2] = vf[q * 4 + 2]; t[3] = vf[q * 4 + 3];
        *(f32x4*)(vred + mt * 32 + q * 8 + hi * 4) = t;
      }
    }
  }

  // ---- matvec: vout[fo] = sum_fi vred[fi] * W3[fi][fo] ----
  float acc0 = 0.f, acc1 = 0.f;
#pragma unroll 8
  for (int f4 = 0; f4 < 32; ++f4) {
    f32x4 vr = *(const f32x4*)(vred + f4 * 4);  // broadcast read
#pragma unroll
    for (int t = 0; t < 4; ++t) {
      float2 w = *(const float2*)(W3g + (f4 * 4 + t) * 128 + n0);
      acc0 += vr[t] * w.x;
      acc1 += vr[t] * w.y;
    }
  }

  // ---- mask + output ----
  float2 b3p = *(const float2*)(b3v + n0);
  float cs0 = csum[n0], cs1 = csum[n1];
  bool c0 = (d0 != 1u) || (cs0 != dv0 * dv0);   // node used as dst or src
  bool c1 = (d1 != 1u) || (cs1 != dv1 * dv1);
  unsigned long long bl0 = __ballot(c0 ? 1 : 0);
  unsigned long long bl1 = __ballot(c1 ? 1 : 0);
  int m0 = bl0 ? 2 * __builtin_ctzll(bl0) : (1 << 30);
  int m1 = bl1 ? 2 * __builtin_ctzll(bl1) + 1 : (1 << 30);
  int minid = m0 < m1 ? m0 : m1;
  float v0 = acc0 * (1.0f / 128.0f) + b3p.x;
  float v1 = acc1 * (1.0f / 128.0f) + b3p.y;
  float2 o;
  o.x = (c0 && n0 != minid) ? NEGV : v0;
  o.y = (c1 && n1 != minid) ? NEGV : v1;
  *(float2*)(out + (size_t)g * 128 + n0) = o;
}

extern "C" void kernel_launch(void* const* d_in, const int* in_sizes, int n_in,
                              void* d_out, int out_size, void* d_ws, size_t ws_size,
                              hipStream_t stream) {
  (void)in_sizes; (void)n_in; (void)out_size; (void)d_ws; (void)ws_size;
  const float* x   = (const float*)d_in[0];
  const int*   ei  = (const int*)d_in[1];
  // d_in[2] = batch (unused; graphs are contiguous 128-node blocks)
  const float* W1  = (const float*)d_in[3];
  const float* b1  = (const float*)d_in[4];
  const float* g1  = (const float*)d_in[5];
  const float* be1 = (const float*)d_in[6];
  const float* rm1 = (const float*)d_in[7];
  const float* rv1 = (const float*)d_in[8];
  const float* W2  = (const float*)d_in[9];
  const float* b2  = (const float*)d_in[10];
  const float* g2  = (const float*)d_in[11];
  const float* be2 = (const float*)d_in[12];
  const float* rm2 = (const float*)d_in[13];
  const float* rv2 = (const float*)d_in[14];
  const float* W3  = (const float*)d_in[15];
  const float* b3  = (const float*)d_in[16];

  prep_w<<<dim3(16), dim3(256), 0, stream>>>(W1, W2);
  gcn_solo<<<dim3(NGRAPH), dim3(64), LDS_SOLO, stream>>>(
      x, ei, b1, g1, be1, rm1, rv1, b2, g2, be2, rm2, rv2, W3, b3,
      (float*)d_out);
}

// Round 10
// 43.944 us; speedup vs baseline: 2.4185x; 1.8069x over previous
//
#include <hip/hip_runtime.h>
#include <hip/hip_bf16.h>

// Fused 3-layer GCN + mean-pool + mask, FP8(e4m3), 3-kernel pipeline:
//   K0 prep_w: W1,W2 -> fragment-ordered fp8 in device-global g_wf
//   K1 xw1:    XW1^T per graph (fp8, swizzled, 16KB/graph) -> d_ws
//   K2 gcn_main<1>: A-build + A@XW1 + BN1 + H1@W2 + A@H2 + BN2 + pool + mask
// Round-10: gcn_main goes to 1024 threads (16 waves; 2 WG/CU = 32 waves/CU,
// FULL occupancy) with ping-pong LDS activation buffers (X0/Y0) so each GEMM
// phase needs ONE barrier (read bufA -> write bufB). 9 barriers total.
// Each wave owns one 32x32 output tile (mt=wid>>2, nt=wid&3), 1 accumulator.
//
// K2 LDS (54276 B): An[0,16K) fp8 swizzled (u4 cnt overlay [0,8K)),
//   X0[16K,32K), Y0[32K,48K) fp8 ping-pong, misc @48K+1K.

#define NGRAPH 512
#define EPG 1024
#define NEDGE (NGRAPH * EPG)
#define NEGV -10000000000.0f
#define LDS_MAIN 54276
#define WS_NEED ((size_t)NGRAPH * 16384)

typedef float f32x16 __attribute__((ext_vector_type(16)));
typedef float f32x4  __attribute__((ext_vector_type(4)));

#define MFMA8(a, b, c) __builtin_amdgcn_mfma_f32_32x32x16_fp8_fp8(a, b, c, 0, 0, 0)

__device__ unsigned char g_wf[32768];   // fp8 W1/W2 fragment buffer

// 128B rows; XOR row into the 8B-slot bits -> 2-way max on b64 reads
__device__ __forceinline__ unsigned swz8(unsigned row, unsigned byte_in_row) {
  return ((row << 7) + byte_in_row) ^ ((row & 15u) << 3);
}

__device__ __forceinline__ unsigned pk4(float a, float b, float c, float d) {
  int r = __builtin_amdgcn_cvt_pk_fp8_f32(a, b, 0, false);
  r = __builtin_amdgcn_cvt_pk_fp8_f32(c, d, r, true);
  return (unsigned)r;
}

// W [fi][fo] f32 -> fragment-ordered fp8 W^T, 8B per (layer,nt,ks,lane)
__global__ void prep_w(const float* __restrict__ W1, const float* __restrict__ W2) {
  int gid = blockIdx.x * 256 + threadIdx.x;     // 0..4095, 8 fp8 each
  int lyr = gid >> 11, r = gid & 2047;
  int lane = r & 63, ks = (r >> 6) & 7, nt = r >> 9;
  const float* W = lyr ? W2 : W1;
  int fo = nt * 32 + (lane & 31);
  int k0 = ks * 16 + (lane >> 5) * 8;
  uint2 o;
  o.x = pk4(W[(k0 + 0) * 128 + fo], W[(k0 + 1) * 128 + fo],
            W[(k0 + 2) * 128 + fo], W[(k0 + 3) * 128 + fo]);
  o.y = pk4(W[(k0 + 4) * 128 + fo], W[(k0 + 5) * 128 + fo],
            W[(k0 + 6) * 128 + fo], W[(k0 + 7) * 128 + fo]);
  ((uint2*)g_wf)[gid] = o;
}

// K1: XW1t[g][fo][node] fp8 swizzled -> ws (one WG per graph, streaming)
__global__ __launch_bounds__(512, 4) void xw1_kernel(
    const float* __restrict__ x, unsigned char* __restrict__ xw1t) {
  extern __shared__ char sm[];
  char* XbL = sm;            // 16K: x fp8 [node][fi] swizzled
  char* OtL = sm + 16384;    // 16K: out staging [fo][node] swizzled

  const int tid = threadIdx.x;
  const int g   = blockIdx.x;
  const int lane = tid & 63;
  const int l31  = lane & 31;
  const int hi   = lane >> 5;
  const int wid  = tid >> 6;
  const int mt   = wid >> 1;
  const int nt0  = (wid & 1) * 2;

  const f32x4* xg = (const f32x4*)(x + (size_t)g * 128 * 128);
  f32x4 xr[8];
#pragma unroll
  for (int j = 0; j < 8; ++j) xr[j] = xg[tid + 512 * j];
#pragma unroll
  for (int j = 0; j < 8; ++j) {
    int k = tid + 512 * j;
    *(unsigned*)(XbL + swz8(k >> 5, (k & 31) * 4)) =
        pk4(xr[j][0], xr[j][1], xr[j][2], xr[j][3]);
  }
  __syncthreads();

  f32x16 c0 = {}, c1 = {};
#pragma unroll
  for (int ks = 0; ks < 8; ++ks) {
    long wA = *(const long*)(g_wf + (nt0 + 0) * 4096 + ks * 512 + lane * 8);
    long wB = *(const long*)(g_wf + (nt0 + 1) * 4096 + ks * 512 + lane * 8);
    long a  = *(const long*)(XbL + swz8(mt * 32 + l31, ks * 16 + hi * 8));
    c0 = MFMA8(a, wA, c0);
    c1 = MFMA8(a, wB, c1);
  }
#pragma unroll
  for (int n = 0; n < 2; ++n) {
    int f = (nt0 + n) * 32 + l31;
    const f32x16& c = n ? c1 : c0;
#pragma unroll
    for (int q = 0; q < 4; ++q) {
      int n0 = mt * 32 + q * 8 + hi * 4;
      *(unsigned*)(OtL + swz8(f, n0)) =
          pk4(c[q * 4 + 0], c[q * 4 + 1], c[q * 4 + 2], c[q * 4 + 3]);
    }
  }
  __syncthreads();

  uint4* dst = (uint4*)(xw1t + (size_t)g * 16384);
#pragma unroll
  for (int it = 0; it < 2; ++it) {
    int idx = tid + 512 * it;
    dst[idx] = ((const uint4*)OtL)[idx];
  }
}

template <int SPLIT>
__global__ __launch_bounds__(1024, 2) void gcn_main(
    const float* __restrict__ x, const int* __restrict__ ei,
    const unsigned char* __restrict__ xw1t,
    const float* __restrict__ b1v, const float* __restrict__ g1v,
    const float* __restrict__ be1v, const float* __restrict__ rm1v,
    const float* __restrict__ rv1v,
    const float* __restrict__ b2v, const float* __restrict__ g2v,
    const float* __restrict__ be2v, const float* __restrict__ rm2v,
    const float* __restrict__ rv2v,
    const float* __restrict__ W3g, const float* __restrict__ b3v,
    float* __restrict__ out) {
  extern __shared__ char sm[];
  char* AnB = sm;                                // fp8 A_norm[128][128] swz
  char* X0  = sm + 16384;                        // ping buffer
  char* Y0  = sm + 32768;                        // pong buffer
  unsigned* cntW = (unsigned*)sm;                // u4 counts overlay [0,8K)
  float*    dis  = (float*)(sm + 49152);
  unsigned* deg  = (unsigned*)(sm + 49664);
  unsigned* conn = (unsigned*)(sm + 50176);
  float*    csum = (float*)(sm + 50688);
  float*    scl1 = (float*)(sm + 51200);
  float*    shf1 = (float*)(sm + 51712);
  float*    scl2 = (float*)(sm + 52224);
  float*    shf2 = (float*)(sm + 52736);
  float*    vred = (float*)(sm + 53248);
  float*    vout = (float*)(sm + 53760);
  int*     minid = (int*)(sm + 54272);

  const int tid = threadIdx.x;                   // 0..1023, 16 waves
  const int g   = blockIdx.x;
  const int lane = tid & 63;
  const int wid  = tid >> 6;                     // 0..15
  const int l31  = lane & 31;
  const int hi   = lane >> 5;
  const int mt   = wid >> 2;                     // A-row tile 0..3
  const int nt   = wid & 3;                      // B-row tile 0..3

  // ---- early global loads ----
  int es, ed;
  { int e = g * EPG + tid; es = ei[e] & 127; ed = ei[NEDGE + e] & 127; }
  uint4 xcp;
  f32x4 xr0, xr1;
  if (SPLIT) {
    xcp = ((const uint4*)(xw1t + (size_t)g * 16384))[tid];
  } else {
    const f32x4* xg = (const f32x4*)(x + (size_t)g * 128 * 128);
    xr0 = xg[tid]; xr1 = xg[tid + 1024];
  }

  // ---- P0: zero cnt, init misc, fill X0 (XW1^T) or Y0 (X) ----
  ((uint2*)cntW)[tid] = make_uint2(0u, 0u);
  if (tid < 128) { deg[tid] = 1u; conn[tid] = 0u; vred[tid] = 0.f; vout[tid] = 0.f; }
  if (tid == 0) *minid = 128;
  if (SPLIT) {
    ((uint4*)X0)[tid] = xcp;
  } else {
    int k1 = tid + 1024;
    *(unsigned*)(Y0 + swz8(tid >> 5, (tid & 31) * 4)) =
        pk4(xr0[0], xr0[1], xr0[2], xr0[3]);
    *(unsigned*)(Y0 + swz8(k1 >> 5, (k1 & 31) * 4)) =
        pk4(xr1[0], xr1[1], xr1[2], xr1[3]);
  }
  __syncthreads();

  // ---- P1: edge atomics (1 edge/thread) + conn flags ----
  atomicAdd(&cntW[ed * 16 + (es >> 3)], 1u << (4 * (es & 7)));
  atomicAdd(&deg[ed], 1u);
  conn[es] = 1u;
  conn[ed] = 1u;
  __syncthreads();

  // ---- P2: params + minid + cnt->regs ----
  uint2 cw2 = ((const uint2*)cntW)[(tid >> 3) * 8 + (tid & 7)];
  if (tid < 128) {
    float dv = rsqrtf((float)deg[tid]);
    dis[tid] = dv;
    csum[tid] = dv * dv;
    float s1 = rsqrtf(rv1v[tid] + 1e-5f) * g1v[tid];
    scl1[tid] = s1;
    shf1[tid] = be1v[tid] + (b1v[tid] - rm1v[tid]) * s1;
    float s2 = rsqrtf(rv2v[tid] + 1e-5f) * g2v[tid];
    scl2[tid] = s2;
    shf2[tid] = be2v[tid] + (b2v[tid] - rm2v[tid]) * s2;
    if (conn[tid]) atomicMin(minid, tid);
  }
  __syncthreads();

  // ---- P3: An decode (16 el/thread, overwrites cnt) + csum atomics ----
  {
    int d = tid >> 3, q = tid & 7;               // row d, cols q*16..+16
    float dd = dis[d];
    int s0 = q * 16;
    f32x4 da = *(const f32x4*)(dis + s0);
    f32x4 db = *(const f32x4*)(dis + s0 + 4);
    f32x4 dc = *(const f32x4*)(dis + s0 + 8);
    f32x4 de = *(const f32x4*)(dis + s0 + 12);
    float dsv[16] = {da[0], da[1], da[2], da[3], db[0], db[1], db[2], db[3],
                     dc[0], dc[1], dc[2], dc[3], de[0], de[1], de[2], de[3]};
    unsigned w0 = cw2.x, w1 = cw2.y;
    float v[16];
#pragma unroll
    for (int i = 0; i < 8; ++i) {
      v[i]     = (float)((w0 >> (4 * i)) & 15u) * dd * dsv[i];
      v[8 + i] = (float)((w1 >> (4 * i)) & 15u) * dd * dsv[8 + i];
    }
    if (d >= s0 && d < s0 + 16) v[d - s0] += dd * dd;   // self loop
    uint2 o0, o1;
    o0.x = pk4(v[0], v[1], v[2], v[3]);   o0.y = pk4(v[4], v[5], v[6], v[7]);
    o1.x = pk4(v[8], v[9], v[10], v[11]); o1.y = pk4(v[12], v[13], v[14], v[15]);
    *(uint2*)(AnB + swz8(d, s0)) = o0;
    *(uint2*)(AnB + swz8(d, s0 + 8)) = o1;
  }
  atomicAdd(&csum[es], dis[es] * dis[ed]);
  __syncthreads();

  // ---- G0 (!SPLIT only): XW1^T = (X @ W1)^T : Y0 x W1 -> X0 ----
  if (!SPLIT) {
    f32x16 a = {};
#pragma unroll
    for (int ks = 0; ks < 8; ++ks) {
      long af = *(const long*)(Y0 + swz8(mt * 32 + l31, ks * 16 + hi * 8));
      long bf = *(const long*)(g_wf + nt * 4096 + ks * 512 + lane * 8);
      a = MFMA8(af, bf, a);
    }
#pragma unroll
    for (int q = 0; q < 4; ++q)
      *(unsigned*)(X0 + swz8(nt * 32 + l31, mt * 32 + q * 8 + hi * 4)) =
          pk4(a[q * 4 + 0], a[q * 4 + 1], a[q * 4 + 2], a[q * 4 + 3]);
    __syncthreads();
  }

  // ---- G1: (A@XW1)^T = X0 x An -> BN1+ReLU -> Y0[d][f] ----
  {
    f32x16 a = {};
#pragma unroll
    for (int ks = 0; ks < 8; ++ks) {
      long af = *(const long*)(X0 + swz8(mt * 32 + l31, ks * 16 + hi * 8));
      long bf = *(const long*)(AnB + swz8(nt * 32 + l31, ks * 16 + hi * 8));
      a = MFMA8(af, bf, a);
    }
    int d = nt * 32 + l31;
#pragma unroll
    for (int q = 0; q < 4; ++q) {
      int f0 = mt * 32 + q * 8 + hi * 4;
      f32x4 s4 = *(const f32x4*)(scl1 + f0);
      f32x4 h4 = *(const f32x4*)(shf1 + f0);
      *(unsigned*)(Y0 + swz8(d, f0)) =
          pk4(fmaxf(a[q * 4 + 0] * s4[0] + h4[0], 0.f),
              fmaxf(a[q * 4 + 1] * s4[1] + h4[1], 0.f),
              fmaxf(a[q * 4 + 2] * s4[2] + h4[2], 0.f),
              fmaxf(a[q * 4 + 3] * s4[3] + h4[3], 0.f));
    }
  }
  __syncthreads();

  // ---- G2: Ht2 = (H1 @ W2)^T : Y0 x W2(L2) -> X0[fo][node] ----
  {
    f32x16 a = {};
#pragma unroll
    for (int ks = 0; ks < 8; ++ks) {
      long af = *(const long*)(Y0 + swz8(mt * 32 + l31, ks * 16 + hi * 8));
      long bf = *(const long*)(g_wf + 16384 + nt * 4096 + ks * 512 + lane * 8);
      a = MFMA8(af, bf, a);
    }
#pragma unroll
    for (int q = 0; q < 4; ++q)
      *(unsigned*)(X0 + swz8(nt * 32 + l31, mt * 32 + q * 8 + hi * 4)) =
          pk4(a[q * 4 + 0], a[q * 4 + 1], a[q * 4 + 2], a[q * 4 + 3]);
  }
  __syncthreads();

  // ---- G3: (A@H2)^T = X0 x An -> BN2+ReLU+csum-weight -> vred ----
  {
    f32x16 a = {};
#pragma unroll
    for (int ks = 0; ks < 8; ++ks) {
      long af = *(const long*)(X0 + swz8(mt * 32 + l31, ks * 16 + hi * 8));
      long bf = *(const long*)(AnB + swz8(nt * 32 + l31, ks * 16 + hi * 8));
      a = MFMA8(af, bf, a);
    }
    float cs = csum[nt * 32 + l31];
#pragma unroll
    for (int q = 0; q < 4; ++q) {
      int f0 = mt * 32 + q * 8 + hi * 4;
      f32x4 s4 = *(const f32x4*)(scl2 + f0);
      f32x4 h4 = *(const f32x4*)(shf2 + f0);
#pragma unroll
      for (int j = 0; j < 4; ++j) {
        float s = cs * fmaxf(a[q * 4 + j] * s4[j] + h4[j], 0.f);
        s += __shfl_xor(s, 1, 32);
        s += __shfl_xor(s, 2, 32);
        s += __shfl_xor(s, 4, 32);
        s += __shfl_xor(s, 8, 32);
        s += __shfl_xor(s, 16, 32);
        if (l31 == 0) atomicAdd(&vred[f0 + j], s);
      }
    }
  }
  __syncthreads();

  // ---- P9: vout[fo] = sum_fi vred[fi] * W3[fi][fo] (8 partials/fo) ----
  {
    int fo = tid & 127, part = tid >> 7;
    float a0 = 0.f;
#pragma unroll
    for (int i = 0; i < 16; ++i) {
      int fi = part * 16 + i;
      a0 += vred[fi] * W3g[fi * 128 + fo];       // coalesced
    }
    atomicAdd(&vout[fo], a0);
  }
  __syncthreads();

  // ---- P10: mask + output ----
  if (tid < 128) {
    bool msk = (conn[tid] != 0u) && (tid != *minid);
    float val = vout[tid] * (1.0f / 128.0f) + b3v[tid];
    out[(size_t)g * 128 + tid] = msk ? NEGV : val;
  }
}

extern "C" void kernel_launch(void* const* d_in, const int* in_sizes, int n_in,
                              void* d_out, int out_size, void* d_ws, size_t ws_size,
                              hipStream_t stream) {
  (void)in_sizes; (void)n_in; (void)out_size;
  const float* x   = (const float*)d_in[0];
  const int*   ei  = (const int*)d_in[1];
  // d_in[2] = batch (unused; graphs are contiguous 128-node blocks)
  const float* W1  = (const float*)d_in[3];
  const float* b1  = (const float*)d_in[4];
  const float* g1  = (const float*)d_in[5];
  const float* be1 = (const float*)d_in[6];
  const float* rm1 = (const float*)d_in[7];
  const float* rv1 = (const float*)d_in[8];
  const float* W2  = (const float*)d_in[9];
  const float* b2  = (const float*)d_in[10];
  const float* g2  = (const float*)d_in[11];
  const float* be2 = (const float*)d_in[12];
  const float* rm2 = (const float*)d_in[13];
  const float* rv2 = (const float*)d_in[14];
  const float* W3  = (const float*)d_in[15];
  const float* b3  = (const float*)d_in[16];
  unsigned char* xw1t = (unsigned char*)d_ws;    // 8 MB XW1^T fp8

  prep_w<<<dim3(16), dim3(256), 0, stream>>>(W1, W2);
  if (ws_size >= WS_NEED) {
    xw1_kernel<<<dim3(NGRAPH), dim3(512), 32768, stream>>>(x, xw1t);
    gcn_main<1><<<dim3(NGRAPH), dim3(1024), LDS_MAIN, stream>>>(
        x, ei, xw1t, b1, g1, be1, rm1, rv1, b2, g2, be2, rm2, rv2, W3, b3,
        (float*)d_out);
  } else {
    gcn_main<0><<<dim3(NGRAPH), dim3(1024), LDS_MAIN, stream>>>(
        x, ei, xw1t, b1, g1, be1, rm1, rv1, b2, g2, be2, rm2, rv2, W3, b3,
        (float*)d_out);
  }
}

// Round 11
// 35.846 us; speedup vs baseline: 2.9649x; 1.2259x over previous
//
#include <hip/hip_runtime.h>
#include <hip/hip_bf16.h>

// Fused 3-layer GCN + mean-pool + mask, FP8(e4m3), SINGLE main kernel:
//   K0 prep_w: W1,W2 -> fragment-ordered fp8 in device-global g_wf (16 WGs)
//   K1 gcn_all: x-stream + A-build + 4 GEMMs + BN + pool + mask, one WG/graph
// Round-11: dropped the xw1 pre-kernel + 8MB ws round-trip (3 launches -> 2).
// 1024 thr (16 waves), ping-pong LDS buffers, 1 barrier per GEMM, 10 total.
// __launch_bounds__(1024,8) caps VGPR at 64 so 2 WGs/CU truly co-reside
// (round 10's (1024,2) allowed 256 VGPR -> co-residency not guaranteed).
//
// LDS (54276 B): An[0,16K) fp8 swizzled (u4 cnt overlay [0,8K)),
//   X0[16K,32K), Y0[32K,48K) fp8 ping-pong, misc @48K.

#define NGRAPH 512
#define EPG 1024
#define NEDGE (NGRAPH * EPG)
#define NEGV -10000000000.0f
#define LDS_MAIN 54276

typedef float f32x16 __attribute__((ext_vector_type(16)));
typedef float f32x4  __attribute__((ext_vector_type(4)));

#define MFMA8(a, b, c) __builtin_amdgcn_mfma_f32_32x32x16_fp8_fp8(a, b, c, 0, 0, 0)

__device__ unsigned char g_wf[32768];   // fp8 W1/W2 fragment buffer

// 128B rows; XOR row into the 8B-slot bits -> 2-way max on b64 reads
__device__ __forceinline__ unsigned swz8(unsigned row, unsigned byte_in_row) {
  return ((row << 7) + byte_in_row) ^ ((row & 15u) << 3);
}

__device__ __forceinline__ unsigned pk4(float a, float b, float c, float d) {
  int r = __builtin_amdgcn_cvt_pk_fp8_f32(a, b, 0, false);
  r = __builtin_amdgcn_cvt_pk_fp8_f32(c, d, r, true);
  return (unsigned)r;
}

// W [fi][fo] f32 -> fragment-ordered fp8 W^T, 8B per (layer,nt,ks,lane)
__global__ void prep_w(const float* __restrict__ W1, const float* __restrict__ W2) {
  int gid = blockIdx.x * 256 + threadIdx.x;     // 0..4095, 8 fp8 each
  int lyr = gid >> 11, r = gid & 2047;
  int lane = r & 63, ks = (r >> 6) & 7, nt = r >> 9;
  const float* W = lyr ? W2 : W1;
  int fo = nt * 32 + (lane & 31);
  int k0 = ks * 16 + (lane >> 5) * 8;
  uint2 o;
  o.x = pk4(W[(k0 + 0) * 128 + fo], W[(k0 + 1) * 128 + fo],
            W[(k0 + 2) * 128 + fo], W[(k0 + 3) * 128 + fo]);
  o.y = pk4(W[(k0 + 4) * 128 + fo], W[(k0 + 5) * 128 + fo],
            W[(k0 + 6) * 128 + fo], W[(k0 + 7) * 128 + fo]);
  ((uint2*)g_wf)[gid] = o;
}

__global__ __launch_bounds__(1024, 8) void gcn_all(
    const float* __restrict__ x, const int* __restrict__ ei,
    const float* __restrict__ b1v, const float* __restrict__ g1v,
    const float* __restrict__ be1v, const float* __restrict__ rm1v,
    const float* __restrict__ rv1v,
    const float* __restrict__ b2v, const float* __restrict__ g2v,
    const float* __restrict__ be2v, const float* __restrict__ rm2v,
    const float* __restrict__ rv2v,
    const float* __restrict__ W3g, const float* __restrict__ b3v,
    float* __restrict__ out) {
  extern __shared__ char sm[];
  char* AnB = sm;                                // fp8 A_norm[128][128] swz
  char* X0  = sm + 16384;                        // ping buffer
  char* Y0  = sm + 32768;                        // pong buffer
  unsigned* cntW = (unsigned*)sm;                // u4 counts overlay [0,8K)
  float*    dis  = (float*)(sm + 49152);
  unsigned* deg  = (unsigned*)(sm + 49664);
  unsigned* conn = (unsigned*)(sm + 50176);
  float*    csum = (float*)(sm + 50688);
  float*    scl1 = (float*)(sm + 51200);
  float*    shf1 = (float*)(sm + 51712);
  float*    scl2 = (float*)(sm + 52224);
  float*    shf2 = (float*)(sm + 52736);
  float*    vred = (float*)(sm + 53248);
  float*    vout = (float*)(sm + 53760);
  int*     minid = (int*)(sm + 54272);

  const int tid = threadIdx.x;                   // 0..1023, 16 waves
  const int g   = blockIdx.x;
  const int lane = tid & 63;
  const int wid  = tid >> 6;                     // 0..15
  const int l31  = lane & 31;
  const int hi   = lane >> 5;
  const int mt   = wid >> 2;                     // A-row tile 0..3
  const int nt   = wid & 3;                      // B-row tile 0..3

  // ---- early global loads (x stream + edges) ----
  int es, ed;
  { int e = g * EPG + tid; es = ei[e] & 127; ed = ei[NEDGE + e] & 127; }
  const f32x4* xg = (const f32x4*)(x + (size_t)g * 128 * 128);
  f32x4 xr0 = xg[tid];
  f32x4 xr1 = xg[tid + 1024];

  // ---- P0: zero cnt, init misc, X -> Y0 fp8 swizzled ----
  ((uint2*)cntW)[tid] = make_uint2(0u, 0u);
  if (tid < 128) { deg[tid] = 1u; conn[tid] = 0u; vred[tid] = 0.f; vout[tid] = 0.f; }
  if (tid == 0) *minid = 128;
  {
    int k1 = tid + 1024;
    *(unsigned*)(Y0 + swz8(tid >> 5, (tid & 31) * 4)) =
        pk4(xr0[0], xr0[1], xr0[2], xr0[3]);
    *(unsigned*)(Y0 + swz8(k1 >> 5, (k1 & 31) * 4)) =
        pk4(xr1[0], xr1[1], xr1[2], xr1[3]);
  }
  __syncthreads();

  // ---- P1: edge atomics (1 edge/thread) + conn flags ----
  atomicAdd(&cntW[ed * 16 + (es >> 3)], 1u << (4 * (es & 7)));
  atomicAdd(&deg[ed], 1u);
  conn[es] = 1u;
  conn[ed] = 1u;
  __syncthreads();

  // ---- P2: dis/csum/BN params + minid + cnt->regs ----
  uint2 cw2 = ((const uint2*)cntW)[tid];         // words 2tid, 2tid+1
  if (tid < 128) {
    float dv = rsqrtf((float)deg[tid]);
    dis[tid] = dv;
    csum[tid] = dv * dv;
    float s1 = rsqrtf(rv1v[tid] + 1e-5f) * g1v[tid];
    scl1[tid] = s1;
    shf1[tid] = be1v[tid] + (b1v[tid] - rm1v[tid]) * s1;
    float s2 = rsqrtf(rv2v[tid] + 1e-5f) * g2v[tid];
    scl2[tid] = s2;
    shf2[tid] = be2v[tid] + (b2v[tid] - rm2v[tid]) * s2;
    if (conn[tid]) atomicMin(minid, tid);
  }
  __syncthreads();

  // ---- P3: An decode (16 el/thread, overwrites cnt) + csum atomics ----
  {
    int d = tid >> 3, q = tid & 7;               // row d, cols q*16..+16
    float dd = dis[d];
#pragma unroll
    for (int hw = 0; hw < 2; ++hw) {             // 8 cols at a time (reg-lean)
      int s0 = q * 16 + hw * 8;
      unsigned w = hw ? cw2.y : cw2.x;
      f32x4 da = *(const f32x4*)(dis + s0);
      f32x4 db = *(const f32x4*)(dis + s0 + 4);
      float v[8];
#pragma unroll
      for (int i = 0; i < 8; ++i)
        v[i] = (float)((w >> (4 * i)) & 15u) * dd * (i < 4 ? da[i] : db[i - 4]);
      if (d >= s0 && d < s0 + 8) v[d - s0] += dd * dd;   // self loop
      uint2 o;
      o.x = pk4(v[0], v[1], v[2], v[3]);
      o.y = pk4(v[4], v[5], v[6], v[7]);
      *(uint2*)(AnB + swz8(d, s0)) = o;
    }
  }
  atomicAdd(&csum[es], dis[es] * dis[ed]);
  __syncthreads();

  // ---- G0: XW1^T = (X @ W1)^T : Y0 x W1 -> X0[fo][node] ----
  {
    f32x16 a = {};
#pragma unroll
    for (int ks = 0; ks < 8; ++ks) {
      long af = *(const long*)(Y0 + swz8(mt * 32 + l31, ks * 16 + hi * 8));
      long bf = *(const long*)(g_wf + nt * 4096 + ks * 512 + lane * 8);
      a = MFMA8(af, bf, a);
    }
#pragma unroll
    for (int q = 0; q < 4; ++q)
      *(unsigned*)(X0 + swz8(nt * 32 + l31, mt * 32 + q * 8 + hi * 4)) =
          pk4(a[q * 4 + 0], a[q * 4 + 1], a[q * 4 + 2], a[q * 4 + 3]);
  }
  __syncthreads();

  // ---- G1: (A@XW1)^T = X0 x An -> BN1+ReLU -> Y0[d][f] ----
  {
    f32x16 a = {};
#pragma unroll
    for (int ks = 0; ks < 8; ++ks) {
      long af = *(const long*)(X0 + swz8(mt * 32 + l31, ks * 16 + hi * 8));
      long bf = *(const long*)(AnB + swz8(nt * 32 + l31, ks * 16 + hi * 8));
      a = MFMA8(af, bf, a);
    }
    int d = nt * 32 + l31;
#pragma unroll
    for (int q = 0; q < 4; ++q) {
      int f0 = mt * 32 + q * 8 + hi * 4;
      f32x4 s4 = *(const f32x4*)(scl1 + f0);
      f32x4 h4 = *(const f32x4*)(shf1 + f0);
      *(unsigned*)(Y0 + swz8(d, f0)) =
          pk4(fmaxf(a[q * 4 + 0] * s4[0] + h4[0], 0.f),
              fmaxf(a[q * 4 + 1] * s4[1] + h4[1], 0.f),
              fmaxf(a[q * 4 + 2] * s4[2] + h4[2], 0.f),
              fmaxf(a[q * 4 + 3] * s4[3] + h4[3], 0.f));
    }
  }
  __syncthreads();

  // ---- G2: Ht2 = (H1 @ W2)^T : Y0 x W2 -> X0[fo][node] ----
  {
    f32x16 a = {};
#pragma unroll
    for (int ks = 0; ks < 8; ++ks) {
      long af = *(const long*)(Y0 + swz8(mt * 32 + l31, ks * 16 + hi * 8));
      long bf = *(const long*)(g_wf + 16384 + nt * 4096 + ks * 512 + lane * 8);
      a = MFMA8(af, bf, a);
    }
#pragma unroll
    for (int q = 0; q < 4; ++q)
      *(unsigned*)(X0 + swz8(nt * 32 + l31, mt * 32 + q * 8 + hi * 4)) =
          pk4(a[q * 4 + 0], a[q * 4 + 1], a[q * 4 + 2], a[q * 4 + 3]);
  }
  __syncthreads();

  // ---- G3: (A@H2)^T = X0 x An -> BN2+ReLU+csum-weight -> vred ----
  {
    f32x16 a = {};
#pragma unroll
    for (int ks = 0; ks < 8; ++ks) {
      long af = *(const long*)(X0 + swz8(mt * 32 + l31, ks * 16 + hi * 8));
      long bf = *(const long*)(AnB + swz8(nt * 32 + l31, ks * 16 + hi * 8));
      a = MFMA8(af, bf, a);
    }
    float cs = csum[nt * 32 + l31];
#pragma unroll
    for (int q = 0; q < 4; ++q) {
      int f0 = mt * 32 + q * 8 + hi * 4;
      f32x4 s4 = *(const f32x4*)(scl2 + f0);
      f32x4 h4 = *(const f32x4*)(shf2 + f0);
#pragma unroll
      for (int j = 0; j < 4; ++j) {
        float s = cs * fmaxf(a[q * 4 + j] * s4[j] + h4[j], 0.f);
        s += __shfl_xor(s, 1, 32);
        s += __shfl_xor(s, 2, 32);
        s += __shfl_xor(s, 4, 32);
        s += __shfl_xor(s, 8, 32);
        s += __shfl_xor(s, 16, 32);
        if (l31 == 0) atomicAdd(&vred[f0 + j], s);
      }
    }
  }
  __syncthreads();

  // ---- P9: vout[fo] = sum_fi vred[fi] * W3[fi][fo] (8 partials/fo) ----
  {
    int fo = tid & 127, part = tid >> 7;
    float a0 = 0.f;
#pragma unroll
    for (int i = 0; i < 16; ++i) {
      int fi = part * 16 + i;
      a0 += vred[fi] * W3g[fi * 128 + fo];       // coalesced
    }
    atomicAdd(&vout[fo], a0);
  }
  __syncthreads();

  // ---- P10: mask + output ----
  if (tid < 128) {
    bool msk = (conn[tid] != 0u) && (tid != *minid);
    float val = vout[tid] * (1.0f / 128.0f) + b3v[tid];
    out[(size_t)g * 128 + tid] = msk ? NEGV : val;
  }
}

extern "C" void kernel_launch(void* const* d_in, const int* in_sizes, int n_in,
                              void* d_out, int out_size, void* d_ws, size_t ws_size,
                              hipStream_t stream) {
  (void)in_sizes; (void)n_in; (void)out_size; (void)d_ws; (void)ws_size;
  const float* x   = (const float*)d_in[0];
  const int*   ei  = (const int*)d_in[1];
  // d_in[2] = batch (unused; graphs are contiguous 128-node blocks)
  const float* W1  = (const float*)d_in[3];
  const float* b1  = (const float*)d_in[4];
  const float* g1  = (const float*)d_in[5];
  const float* be1 = (const float*)d_in[6];
  const float* rm1 = (const float*)d_in[7];
  const float* rv1 = (const float*)d_in[8];
  const float* W2  = (const float*)d_in[9];
  const float* b2  = (const float*)d_in[10];
  const float* g2  = (const float*)d_in[11];
  const float* be2 = (const float*)d_in[12];
  const float* rm2 = (const float*)d_in[13];
  const float* rv2 = (const float*)d_in[14];
  const float* W3  = (const float*)d_in[15];
  const float* b3  = (const float*)d_in[16];

  prep_w<<<dim3(16), dim3(256), 0, stream>>>(W1, W2);
  gcn_all<<<dim3(NGRAPH), dim3(1024), LDS_MAIN, stream>>>(
      x, ei, b1, g1, be1, rm1, rv1, b2, g2, be2, rm2, rv2, W3, b3,
      (float*)d_out);
}